// Round 2
// baseline (37.883 us; speedup 1.0000x reference)
//
#include <hip/hip_runtime.h>

// UpsampleFlow2: Gaussian Nadaraya-Watson upsampling.
// out [B,3,N] = (sum_s k*f) / (sum_s k), k = exp(-|x-y|^2/r^2).
// exp(-|x|^2/r^2) cancels in num/den -> k' = exp2(c2*dot(x,y) + cy*|y|^2).
//
// R2: occupancy fix. R1 had 512 blocks = 2 waves/SIMD (latency-exposed, ~4x
// VALU floor). Now PPT=2, SC=32 -> 2048 blocks = 8 waves/SIMD.
// Partial traffic: 32x512KB = 16MB write + 16MB read (~5us HBM) -- cheap.

constexpr int B_ = 4, N_ = 8192, S_ = 2048;
constexpr int BLOCK = 256, PPT = 2;
constexpr int PTS_PER_BLOCK = BLOCK * PPT;      // 512
constexpr int NB = (B_ * N_) / PTS_PER_BLOCK;   // 64 n-blocks (16 per batch)
constexpr int NB_PER_B = N_ / PTS_PER_BLOCK;    // 16
constexpr int BN = B_ * N_;                     // 32768
constexpr float LOG2E = 1.4426950408889634f;

template <int CHUNK>
__global__ __launch_bounds__(BLOCK, 6) void uf2_partial(
    const float* __restrict__ xyz,
    const float* __restrict__ sxyz,
    const float* __restrict__ sflow,
    const int* __restrict__ resol,
    float4* __restrict__ part)
{
    __shared__ float4 As[CHUNK];   // (yx, yy, yz, cy*|y|^2)
    __shared__ float4 Fs[CHUNK];   // (fx, fy, fz, 0)

    const int nb = blockIdx.x % NB;
    const int sc = blockIdx.x / NB;
    const int b  = nb / NB_PER_B;
    const int n0 = (nb % NB_PER_B) * PTS_PER_BLOCK;
    const int s0 = sc * CHUNK;

    const float r      = (float)resol[0];       // INITIAL_RADIUS (=1) * resol
    const float inv_r2 = 1.0f / (r * r);
    const float c2 = 2.0f * inv_r2 * LOG2E;
    const float cy = -inv_r2 * LOG2E;

    // ---- stage sparse chunk into LDS (coalesced) ----
    const float* ybase = sxyz  + b * 3 * S_;
    const float* fbase = sflow + b * 3 * S_;
    for (int t = threadIdx.x; t < CHUNK; t += BLOCK) {
        const int s = s0 + t;
        const float yx = ybase[s], yy = ybase[S_ + s], yz = ybase[2 * S_ + s];
        const float fx = fbase[s], fy = fbase[S_ + s], fz = fbase[2 * S_ + s];
        As[t] = make_float4(yx, yy, yz, cy * (yx * yx + yy * yy + yz * yz));
        Fs[t] = make_float4(fx, fy, fz, 0.0f);
    }
    __syncthreads();

    // ---- per-thread query points ----
    const float* xbase = xyz + b * 3 * N_;
    float px[PPT], py[PPT], pz[PPT];
    float4 acc[PPT];
#pragma unroll
    for (int p = 0; p < PPT; ++p) {
        const int n = n0 + threadIdx.x + p * BLOCK;
        px[p] = xbase[n];
        py[p] = xbase[N_ + n];
        pz[p] = xbase[2 * N_ + n];
        acc[p] = make_float4(0.f, 0.f, 0.f, 0.f);
    }

    // ---- main loop over sparse chunk ----
#pragma unroll 4
    for (int t = 0; t < CHUNK; ++t) {
        const float4 a = As[t];   // broadcast ds_read_b128
        const float4 f = Fs[t];
#pragma unroll
        for (int p = 0; p < PPT; ++p) {
            float dot = px[p] * a.x;
            dot = fmaf(py[p], a.y, dot);
            dot = fmaf(pz[p], a.z, dot);
            const float k = __builtin_amdgcn_exp2f(fmaf(dot, c2, a.w));
            acc[p].x = fmaf(k, f.x, acc[p].x);
            acc[p].y = fmaf(k, f.y, acc[p].y);
            acc[p].z = fmaf(k, f.z, acc[p].z);
            acc[p].w += k;
        }
    }

    // ---- write partials (coalesced float4) ----
#pragma unroll
    for (int p = 0; p < PPT; ++p) {
        const int g = b * N_ + n0 + threadIdx.x + p * BLOCK;
        part[(size_t)sc * BN + g] = acc[p];
    }
}

__global__ __launch_bounds__(256) void uf2_combine(
    const float4* __restrict__ part, float* __restrict__ out, int SC)
{
    const int g = blockIdx.x * 256 + threadIdx.x;   // 0..BN-1
    float4 s = make_float4(0.f, 0.f, 0.f, 0.f);
    for (int c = 0; c < SC; ++c) {
        const float4 p = part[(size_t)c * BN + g];
        s.x += p.x; s.y += p.y; s.z += p.z; s.w += p.w;
    }
    const float inv = 1.0f / s.w;
    const int b = g >> 13;            // /8192
    const int n = g & (N_ - 1);
    float* ob = out + b * 3 * N_;
    ob[n]          = s.x * inv;
    ob[N_ + n]     = s.y * inv;
    ob[2 * N_ + n] = s.z * inv;
}

// Fallback if workspace is too small for even one partial chunk:
// single kernel, full S staged in LDS (64 KB), writes out directly.
__global__ __launch_bounds__(BLOCK, 1) void uf2_fused(
    const float* __restrict__ xyz,
    const float* __restrict__ sxyz,
    const float* __restrict__ sflow,
    const int* __restrict__ resol,
    float* __restrict__ out)
{
    __shared__ float4 As[S_];
    __shared__ float4 Fs[S_];

    const int nb = blockIdx.x;
    const int b  = nb / NB_PER_B;
    const int n0 = (nb % NB_PER_B) * PTS_PER_BLOCK;

    const float r      = (float)resol[0];
    const float inv_r2 = 1.0f / (r * r);
    const float c2 = 2.0f * inv_r2 * LOG2E;
    const float cy = -inv_r2 * LOG2E;

    const float* ybase = sxyz  + b * 3 * S_;
    const float* fbase = sflow + b * 3 * S_;
    for (int t = threadIdx.x; t < S_; t += BLOCK) {
        const float yx = ybase[t], yy = ybase[S_ + t], yz = ybase[2 * S_ + t];
        const float fx = fbase[t], fy = fbase[S_ + t], fz = fbase[2 * S_ + t];
        As[t] = make_float4(yx, yy, yz, cy * (yx * yx + yy * yy + yz * yz));
        Fs[t] = make_float4(fx, fy, fz, 0.0f);
    }
    __syncthreads();

    const float* xbase = xyz + b * 3 * N_;
    float px[PPT], py[PPT], pz[PPT];
    float4 acc[PPT];
#pragma unroll
    for (int p = 0; p < PPT; ++p) {
        const int n = n0 + threadIdx.x + p * BLOCK;
        px[p] = xbase[n];
        py[p] = xbase[N_ + n];
        pz[p] = xbase[2 * N_ + n];
        acc[p] = make_float4(0.f, 0.f, 0.f, 0.f);
    }

#pragma unroll 4
    for (int t = 0; t < S_; ++t) {
        const float4 a = As[t];
        const float4 f = Fs[t];
#pragma unroll
        for (int p = 0; p < PPT; ++p) {
            float dot = px[p] * a.x;
            dot = fmaf(py[p], a.y, dot);
            dot = fmaf(pz[p], a.z, dot);
            const float k = __builtin_amdgcn_exp2f(fmaf(dot, c2, a.w));
            acc[p].x = fmaf(k, f.x, acc[p].x);
            acc[p].y = fmaf(k, f.y, acc[p].y);
            acc[p].z = fmaf(k, f.z, acc[p].z);
            acc[p].w += k;
        }
    }

#pragma unroll
    for (int p = 0; p < PPT; ++p) {
        const int n = n0 + threadIdx.x + p * BLOCK;
        const float inv = 1.0f / acc[p].w;
        float* ob = out + b * 3 * N_;
        ob[n]          = acc[p].x * inv;
        ob[N_ + n]     = acc[p].y * inv;
        ob[2 * N_ + n] = acc[p].z * inv;
    }
}

extern "C" void kernel_launch(void* const* d_in, const int* in_sizes, int n_in,
                              void* d_out, int out_size, void* d_ws, size_t ws_size,
                              hipStream_t stream)
{
    const float* xyz   = (const float*)d_in[0];
    const float* sxyz  = (const float*)d_in[1];
    const float* sflow = (const float*)d_in[2];
    const int*   resol = (const int*)d_in[3];
    float* out   = (float*)d_out;
    float4* part = (float4*)d_ws;

    const size_t per_chunk = (size_t)BN * sizeof(float4);   // 512 KB
    int SC = 32;
    while (SC > 1 && (size_t)SC * per_chunk > ws_size) SC >>= 1;

    if ((size_t)SC * per_chunk > ws_size) {
        // workspace too small even for SC=1 -> fused fallback (slower, correct)
        uf2_fused<<<dim3(NB), dim3(BLOCK), 0, stream>>>(xyz, sxyz, sflow, resol, out);
        return;
    }

    dim3 grid(NB * SC), blk(BLOCK);
    switch (SC) {
        case 32: uf2_partial<S_ / 32><<<grid, blk, 0, stream>>>(xyz, sxyz, sflow, resol, part); break;
        case 16: uf2_partial<S_ / 16><<<grid, blk, 0, stream>>>(xyz, sxyz, sflow, resol, part); break;
        case 8:  uf2_partial<S_ / 8 ><<<grid, blk, 0, stream>>>(xyz, sxyz, sflow, resol, part); break;
        case 4:  uf2_partial<S_ / 4 ><<<grid, blk, 0, stream>>>(xyz, sxyz, sflow, resol, part); break;
        case 2:  uf2_partial<S_ / 2 ><<<grid, blk, 0, stream>>>(xyz, sxyz, sflow, resol, part); break;
        default: uf2_partial<S_     ><<<grid, blk, 0, stream>>>(xyz, sxyz, sflow, resol, part); break;
    }
    uf2_combine<<<dim3(BN / 256), dim3(256), 0, stream>>>(part, out, SC);
}

// Round 3
// 32.583 us; speedup vs baseline: 1.1627x; 1.1627x over previous
//
#include <hip/hip_runtime.h>

// UpsampleFlow2: Gaussian Nadaraya-Watson upsampling.
// out [B,3,N] = (sum_s k*f)/(sum_s k), k = exp(-|x-y|^2/r^2).
// exp(-|x|^2/r^2) cancels in num/den. Further factor exp(-|y|^2/r^2) = ky
// OUT of the exponent and fold it into f (and the denominator weight):
//   k' = exp2(c2*dot(x,y)) * ky,  c2 = 2*log2e/r^2, ky = exp2(-log2e*|y|^2/r^2)
// -> inner loop: mul+2fma (dot) + exp2 + 4 fma, each instr <=1 SGPR operand.
//
// R3: sparse data is WAVE-UNIFORM -> move it out of LDS into SGPRs.
// R1/R2 were LDS-pipe-bound (2 broadcast ds_read_b128 per t per wave; R2's
// PPT halving doubled ds_reads and regressed). A prep kernel packs per-s
// constants into 32B structs in d_ws; the main loop reads them with uniform
// addresses (const __restrict__) -> s_load_dwordx8 on the scalar pipe.

typedef __attribute__((ext_vector_type(8))) float f8;

constexpr int B_ = 4, N_ = 8192, S_ = 2048;
constexpr int BLOCK = 256;
constexpr int NBPB = N_ / BLOCK;        // 32 n-blocks per batch
constexpr int NB = B_ * NBPB;           // 128 n-blocks
constexpr int BN = B_ * N_;             // 32768
constexpr float LOG2E = 1.4426950408889634f;

__global__ __launch_bounds__(BLOCK) void uf2_prep(
    const float* __restrict__ sxyz,
    const float* __restrict__ sflow,
    const int* __restrict__ resol,
    f8* __restrict__ P)
{
    const int i = blockIdx.x * BLOCK + threadIdx.x;   // 0..B_*S_-1
    const int b = i / S_;
    const int s = i - b * S_;
    const float r = (float)resol[0];                  // INITIAL_RADIUS(=1)*resol
    const float inv_r2 = 1.0f / (r * r);
    const float c2 = 2.0f * inv_r2 * LOG2E;
    const float cy = -inv_r2 * LOG2E;
    const float* yb = sxyz  + b * 3 * S_;
    const float* fb = sflow + b * 3 * S_;
    const float yx = yb[s], yy = yb[S_ + s], yz = yb[2 * S_ + s];
    const float fx = fb[s], fy = fb[S_ + s], fz = fb[2 * S_ + s];
    const float ky = __builtin_amdgcn_exp2f(cy * (yx * yx + yy * yy + yz * yz));
    f8 v;
    v[0] = c2 * yx; v[1] = c2 * yy; v[2] = c2 * yz; v[3] = 0.0f;
    v[4] = ky * fx; v[5] = ky * fy; v[6] = ky * fz; v[7] = ky;
    P[i] = v;
}

template <int CHUNK>
__global__ __launch_bounds__(BLOCK) void uf2_main(
    const float* __restrict__ xyz,
    const f8* __restrict__ P,
    float4* __restrict__ part)
{
    const int nb = blockIdx.x % NB;
    const int sc = blockIdx.x / NB;
    const int b  = nb / NBPB;
    const int n  = (nb % NBPB) * BLOCK + threadIdx.x;

    const float* xb = xyz + b * 3 * N_;
    const float px = xb[n], py = xb[N_ + n], pz = xb[2 * N_ + n];

    const f8* __restrict__ p = P + b * S_ + sc * CHUNK;   // uniform address

    float ax = 0.f, ay = 0.f, az = 0.f, aw = 0.f;
#pragma unroll 8
    for (int t = 0; t < CHUNK; ++t) {
        const f8 v = p[t];   // wave-uniform -> s_load_dwordx8 (scalar pipe)
        float e = fmaf(px, v[0], fmaf(py, v[1], pz * v[2]));
        const float k = __builtin_amdgcn_exp2f(e);
        ax = fmaf(k, v[4], ax);
        ay = fmaf(k, v[5], ay);
        az = fmaf(k, v[6], az);
        aw = fmaf(k, v[7], aw);
    }

    const int g = b * N_ + n;
    part[(size_t)sc * BN + g] = make_float4(ax, ay, az, aw);
}

__global__ __launch_bounds__(BLOCK) void uf2_combine(
    const float4* __restrict__ part, float* __restrict__ out, int SC)
{
    const int g = blockIdx.x * BLOCK + threadIdx.x;   // 0..BN-1
    float4 s = make_float4(0.f, 0.f, 0.f, 0.f);
    for (int c = 0; c < SC; ++c) {
        const float4 p = part[(size_t)c * BN + g];
        s.x += p.x; s.y += p.y; s.z += p.z; s.w += p.w;
    }
    const float inv = 1.0f / s.w;
    const int b = g >> 13;            // /8192
    const int n = g & (N_ - 1);
    float* ob = out + b * 3 * N_;
    ob[n]          = s.x * inv;
    ob[N_ + n]     = s.y * inv;
    ob[2 * N_ + n] = s.z * inv;
}

// Fallback (ws too small): single kernel, full S staged in LDS, direct out.
__global__ __launch_bounds__(BLOCK, 1) void uf2_fused(
    const float* __restrict__ xyz,
    const float* __restrict__ sxyz,
    const float* __restrict__ sflow,
    const int* __restrict__ resol,
    float* __restrict__ out)
{
    constexpr int PPT = 4;
    constexpr int PTS = BLOCK * PPT;
    __shared__ float4 As[S_];
    __shared__ float4 Fs[S_];

    const int nb = blockIdx.x;
    const int b  = nb / (N_ / PTS);
    const int n0 = (nb % (N_ / PTS)) * PTS;

    const float r = (float)resol[0];
    const float inv_r2 = 1.0f / (r * r);
    const float c2 = 2.0f * inv_r2 * LOG2E;
    const float cy = -inv_r2 * LOG2E;

    const float* yb = sxyz  + b * 3 * S_;
    const float* fb = sflow + b * 3 * S_;
    for (int t = threadIdx.x; t < S_; t += BLOCK) {
        const float yx = yb[t], yy = yb[S_ + t], yz = yb[2 * S_ + t];
        const float fx = fb[t], fy = fb[S_ + t], fz = fb[2 * S_ + t];
        As[t] = make_float4(yx, yy, yz, cy * (yx * yx + yy * yy + yz * yz));
        Fs[t] = make_float4(fx, fy, fz, 0.0f);
    }
    __syncthreads();

    const float* xb = xyz + b * 3 * N_;
    float px[PPT], py[PPT], pz[PPT];
    float4 acc[PPT];
#pragma unroll
    for (int p = 0; p < PPT; ++p) {
        const int n = n0 + threadIdx.x + p * BLOCK;
        px[p] = xb[n]; py[p] = xb[N_ + n]; pz[p] = xb[2 * N_ + n];
        acc[p] = make_float4(0.f, 0.f, 0.f, 0.f);
    }
#pragma unroll 4
    for (int t = 0; t < S_; ++t) {
        const float4 a = As[t];
        const float4 f = Fs[t];
#pragma unroll
        for (int p = 0; p < PPT; ++p) {
            float dot = px[p] * a.x;
            dot = fmaf(py[p], a.y, dot);
            dot = fmaf(pz[p], a.z, dot);
            const float k = __builtin_amdgcn_exp2f(fmaf(dot, c2, a.w));
            acc[p].x = fmaf(k, f.x, acc[p].x);
            acc[p].y = fmaf(k, f.y, acc[p].y);
            acc[p].z = fmaf(k, f.z, acc[p].z);
            acc[p].w += k;
        }
    }
#pragma unroll
    for (int p = 0; p < PPT; ++p) {
        const int n = n0 + threadIdx.x + p * BLOCK;
        const float inv = 1.0f / acc[p].w;
        float* ob = out + b * 3 * N_;
        ob[n]          = acc[p].x * inv;
        ob[N_ + n]     = acc[p].y * inv;
        ob[2 * N_ + n] = acc[p].z * inv;
    }
}

extern "C" void kernel_launch(void* const* d_in, const int* in_sizes, int n_in,
                              void* d_out, int out_size, void* d_ws, size_t ws_size,
                              hipStream_t stream)
{
    const float* xyz   = (const float*)d_in[0];
    const float* sxyz  = (const float*)d_in[1];
    const float* sflow = (const float*)d_in[2];
    const int*   resol = (const int*)d_in[3];
    float* out = (float*)d_out;

    // workspace layout: P (256KB, padded to 1MB) | partials (SC x 512KB)
    const size_t P_bytes = (size_t)1 << 20;
    const size_t per_chunk = (size_t)BN * sizeof(float4);   // 512 KB
    int SC = 16;
    while (SC > 1 && P_bytes + (size_t)SC * per_chunk > ws_size) SC >>= 1;

    if (P_bytes + (size_t)SC * per_chunk > ws_size) {
        uf2_fused<<<dim3(BN / 1024), dim3(BLOCK), 0, stream>>>(
            xyz, sxyz, sflow, resol, out);
        return;
    }

    f8* P = (f8*)d_ws;
    float4* part = (float4*)((char*)d_ws + P_bytes);

    uf2_prep<<<dim3((B_ * S_) / BLOCK), dim3(BLOCK), 0, stream>>>(
        sxyz, sflow, resol, P);

    dim3 grid(NB * SC), blk(BLOCK);
    switch (SC) {
        case 16: uf2_main<S_ / 16><<<grid, blk, 0, stream>>>(xyz, P, part); break;
        case 8:  uf2_main<S_ / 8 ><<<grid, blk, 0, stream>>>(xyz, P, part); break;
        case 4:  uf2_main<S_ / 4 ><<<grid, blk, 0, stream>>>(xyz, P, part); break;
        case 2:  uf2_main<S_ / 2 ><<<grid, blk, 0, stream>>>(xyz, P, part); break;
        default: uf2_main<S_     ><<<grid, blk, 0, stream>>>(xyz, P, part); break;
    }
    uf2_combine<<<dim3(BN / BLOCK), dim3(BLOCK), 0, stream>>>(part, out, SC);
}